// Round 3
// baseline (554.300 us; speedup 1.0000x reference)
//
#include <hip/hip_runtime.h>
#include <hip/hip_bf16.h>
#include <stdint.h>

#define B_   256
#define C_   10
#define S_   500
#define H_   256
#define OUT_ 500
#define M_   (B_ * S_)   // 128000 LSTM rows
#define FCK  (S_ * H_)   // 128000 fc inner dim

typedef __attribute__((ext_vector_type(8))) short s16x8;   // 8 bf16
typedef __attribute__((ext_vector_type(4))) float f32x4;

__device__ __forceinline__ unsigned short f2bf(float f) {
  union { float f; unsigned u; } v; v.f = f;
  unsigned r = v.u + 0x7fffu + ((v.u >> 16) & 1u);   // RNE
  return (unsigned short)(r >> 16);
}
__device__ __forceinline__ float sigf(float x) { return 1.0f / (1.0f + __expf(-x)); }
__device__ __forceinline__ float tanh_f(float x) { return 1.0f - 2.0f / (__expf(2.0f * x) + 1.0f); }

__device__ __forceinline__ void gload16(const void* g, void* l) {
  __builtin_amdgcn_global_load_lds((const __attribute__((address_space(1))) void*)g,
                                   (__attribute__((address_space(3))) void*)l, 16, 0, 0);
}

// ---- conv center tap + relu ----
__global__ void k_conv(const float* __restrict__ x, const float* __restrict__ cw,
                       const float* __restrict__ cb, float* __restrict__ y) {
  int n = blockIdx.x * 256 + threadIdx.x;            // 128000 exact
  int b = n / S_, s = n - b * S_;
  const float* xp = x + (size_t)b * C_ * S_ + s;
  float acc = cb[0];
#pragma unroll
  for (int c = 0; c < C_; ++c) acc += xp[c * S_] * cw[c * 5 + 2];
  y[n] = fmaxf(acc, 0.0f);
}

// ---- w_ih1 fp32 -> bf16 ----
__global__ void k_cvtw1(const float* __restrict__ w, unsigned short* __restrict__ wb) {
  int i = blockIdx.x * 256 + threadIdx.x;            // 262144 exact
  wb[i] = f2bf(w[i]);
}

// ---- LSTM0 (scalar input, zero state, f-gate dead): h0[n][k] bf16 ----
__global__ void k_h0(const float* __restrict__ y, const float* __restrict__ w0,
                     const float* __restrict__ bi0, const float* __restrict__ bh0,
                     unsigned short* __restrict__ h0) {
  int gid = blockIdx.x * 256 + threadIdx.x;          // 8,192,000 exact
  int n = gid >> 6, q = gid & 63;
  int k = q * 4;
  float yv = y[n];
  f32x4 wi = *(const f32x4*)&w0[k];
  f32x4 wg = *(const f32x4*)&w0[512 + k];
  f32x4 wo = *(const f32x4*)&w0[768 + k];
  f32x4 bii = *(const f32x4*)&bi0[k];
  f32x4 big = *(const f32x4*)&bi0[512 + k];
  f32x4 bio = *(const f32x4*)&bi0[768 + k];
  f32x4 bhi = *(const f32x4*)&bh0[k];
  f32x4 bhg = *(const f32x4*)&bh0[512 + k];
  f32x4 bho = *(const f32x4*)&bh0[768 + k];
  ushort4 o;
  unsigned short* op = (unsigned short*)&o;
#pragma unroll
  for (int j = 0; j < 4; ++j) {
    float gi = yv * wi[j] + bii[j] + bhi[j];
    float gg = yv * wg[j] + big[j] + bhg[j];
    float go = yv * wo[j] + bio[j] + bho[j];
    float c = sigf(gi) * tanh_f(gg);
    op[j] = f2bf(sigf(go) * tanh_f(c));
  }
  *(ushort4*)&h0[(size_t)n * 256 + k] = o;
}

// ---- GEMM1: zero-LDS, zero-barrier. gates = h0 @ Wb^T, fused act -> h1 bf16 ----
// BM=128 (4 waves x 32 rows), 64 k-cols x 3 gates per block, K=256
__global__ __launch_bounds__(256, 3) void k_gemm1(
    const unsigned short* __restrict__ A,    // h0 [M][256] bf16
    const unsigned short* __restrict__ Wb,   // [1024][256] bf16
    const float* __restrict__ b1i, const float* __restrict__ b1h,
    unsigned short* __restrict__ h1) {
  const int t = threadIdx.x, lane = t & 63, w = t >> 6;
  const int m0 = blockIdx.x * 128;
  const int kc0 = blockIdx.y * 64;
  f32x4 acc[2][3][4] = {};

  const unsigned short* arow = A + (size_t)(m0 + w * 32 + (lane & 15)) * 256 + ((lane >> 4) * 8);
  const unsigned short* brow = Wb + (size_t)(kc0 + (lane & 15)) * 256 + ((lane >> 4) * 8);

#pragma unroll
  for (int ks = 0; ks < 8; ++ks) {            // 8 K-steps of 32
    const int kof = ks * 32;
    s16x8 a0 = *(const s16x8*)(arow + kof);
    s16x8 a1 = *(const s16x8*)(arow + 16 * 256 + kof);
#pragma unroll
    for (int g = 0; g < 3; ++g) {
      const size_t gb = (size_t)((g == 0) ? 0 : (g == 1 ? 512 : 768)) * 256;
#pragma unroll
      for (int n = 0; n < 4; ++n) {
        s16x8 b = *(const s16x8*)(brow + gb + (size_t)(n * 16) * 256 + kof);
        acc[0][g][n] = __builtin_amdgcn_mfma_f32_16x16x32_bf16(a0, b, acc[0][g][n], 0, 0, 0);
        acc[1][g][n] = __builtin_amdgcn_mfma_f32_16x16x32_bf16(a1, b, acc[1][g][n], 0, 0, 0);
      }
    }
  }
  // epilogue: h = sig(go)*tanh(sig(gi)*tanh(gg))
#pragma unroll
  for (int n = 0; n < 4; ++n) {
    int kglob = kc0 + n * 16 + (lane & 15);
    float bi = b1i[kglob] + b1h[kglob];
    float bg = b1i[512 + kglob] + b1h[512 + kglob];
    float bo = b1i[768 + kglob] + b1h[768 + kglob];
#pragma unroll
    for (int m = 0; m < 2; ++m) {
#pragma unroll
      for (int r = 0; r < 4; ++r) {
        int row = m0 + w * 32 + m * 16 + (lane >> 4) * 4 + r;
        float gi = acc[m][0][n][r] + bi;
        float gg = acc[m][1][n][r] + bg;
        float go = acc[m][2][n][r] + bo;
        float c = sigf(gi) * tanh_f(gg);
        h1[(size_t)row * 256 + kglob] = f2bf(sigf(go) * tanh_f(c));
      }
    }
  }
}

// ---- out init: out[b][o] = fc_b[o] ----
__global__ void k_initout(const float* __restrict__ fcb, float* __restrict__ out) {
  int i = blockIdx.x * 256 + threadIdx.x;            // 128000 exact
  out[i] = fcb[i % OUT_];
}

// ---- GEMM2: out += h1(flat [256][128000]) @ fc_w^T ; split-K + atomics ----
// BM=256, BN=128, Kchunk=1024 (grid 4 x 125). A direct->regs; W double-buffered
// swizzled LDS (chunk ^ (row&15)), 2-phase pipeline, one barrier/iter.
__global__ __launch_bounds__(512, 4) void k_gemm2(
    const unsigned short* __restrict__ A,    // h1 viewed [256][128000] bf16
    const float* __restrict__ W,             // fc_w [500][128000] f32
    float* __restrict__ out) {
  __shared__ __align__(16) float Ws[2][128 * 64];        // 2 x 32 KB
  const int t = threadIdx.x, lane = t & 63;
  const int w = t >> 6, wm = w >> 1, wn = w & 1;
  const int n0 = blockIdx.x * 128;
  const size_t kbase = (size_t)blockIdx.y * 1024;
  f32x4 acc[4][4] = {};

  // W stage: 2048 chunks of 16B; LDS dest linear per-lane, swizzle on SOURCE.
  // LDS[row][c] <- global f32s [ (c^(row&15))*4 .. +3 ]  (involution)
#define STAGE_W(buf, kofs)                                                    \
  {                                                                           \
    _Pragma("unroll")                                                         \
    for (int it = 0; it < 4; ++it) {                                          \
      int q = it * 512 + t;                                                   \
      int r = q >> 4, c = q & 15;                                             \
      int nrow = n0 + r; if (nrow > 499) nrow = 499;                          \
      int cs = c ^ (r & 15);                                                  \
      gload16(W + (size_t)nrow * FCK + (kofs) + (cs << 2),                    \
              (void*)&Ws[buf][q * 4]);                                        \
    }                                                                         \
  }

  STAGE_W(0, kbase);
  __syncthreads();

  int cur = 0;
  for (int kt = 0; kt < 16; ++kt) {
    // 1) A fragments (global->reg) FIRST so their wait is a counted vmcnt
    //    that leaves the just-issued W stage in flight.
    s16x8 af[4][2];
#pragma unroll
    for (int m = 0; m < 4; ++m) {
      const unsigned short* ap =
          A + (size_t)(wm * 64 + m * 16 + (lane & 15)) * FCK + kbase + kt * 64 + ((lane >> 4) * 8);
#pragma unroll
      for (int kk = 0; kk < 2; ++kk) af[m][kk] = *(const s16x8*)(ap + kk * 32);
    }
    // 2) stage next W tile into the other buffer
    int ktn = (kt < 15) ? (kt + 1) : 15;
    STAGE_W(cur ^ 1, kbase + (size_t)ktn * 64);
    // 3) compute from Ws[cur] (swizzled reads -> 2-way, free)
#pragma unroll
    for (int kk = 0; kk < 2; ++kk) {
      const int ko = kk * 32 + (lane >> 4) * 8;   // f32 units
      const int c0 = ko >> 2;
#pragma unroll
      for (int n = 0; n < 4; ++n) {
        const int br = wn * 64 + n * 16 + (lane & 15);
        const int cA = c0 ^ (br & 15), cB = (c0 + 1) ^ (br & 15);
        f32x4 w0 = *(const f32x4*)&Ws[cur][(br * 16 + cA) * 4];
        f32x4 w1 = *(const f32x4*)&Ws[cur][(br * 16 + cB) * 4];
        s16x8 b;
#pragma unroll
        for (int j = 0; j < 4; ++j) {
          b[j] = (short)f2bf(w0[j]);
          b[4 + j] = (short)f2bf(w1[j]);
        }
#pragma unroll
        for (int m = 0; m < 4; ++m)
          acc[m][kk == 0 ? n : n] = acc[m][n];   // no-op keep shape clear
#pragma unroll
        for (int m = 0; m < 4; ++m)
          acc[m][n] = __builtin_amdgcn_mfma_f32_16x16x32_bf16(af[m][kk], b, acc[m][n], 0, 0, 0);
      }
    }
    __syncthreads();   // drains vmcnt (W next tile) + lgkm; buffer swap safe
    cur ^= 1;
  }

#pragma unroll
  for (int m = 0; m < 4; ++m) {
#pragma unroll
    for (int n = 0; n < 4; ++n) {
      int col = n0 + wn * 64 + n * 16 + (lane & 15);
      if (col < OUT_) {
#pragma unroll
        for (int r = 0; r < 4; ++r) {
          int row = wm * 64 + m * 16 + (lane >> 4) * 4 + r;
          atomicAdd(&out[(size_t)row * OUT_ + col], acc[m][n][r]);
        }
      }
    }
  }
#undef STAGE_W
}

extern "C" void kernel_launch(void* const* d_in, const int* in_sizes, int n_in,
                              void* d_out, int out_size, void* d_ws, size_t ws_size,
                              hipStream_t stream) {
  const float* x      = (const float*)d_in[0];
  const float* conv_w = (const float*)d_in[1];
  const float* conv_b = (const float*)d_in[2];
  const float* w_ih0  = (const float*)d_in[3];
  const float* b_ih0  = (const float*)d_in[4];
  const float* b_hh0  = (const float*)d_in[5];
  const float* w_ih1  = (const float*)d_in[6];
  const float* b_ih1  = (const float*)d_in[7];
  const float* b_hh1  = (const float*)d_in[8];
  const float* fc_w   = (const float*)d_in[9];
  const float* fc_b   = (const float*)d_in[10];
  float* out = (float*)d_out;

  char* ws = (char*)d_ws;
  float* y            = (float*)ws;                              // 512000 B
  unsigned short* w1b = (unsigned short*)(ws + 512000);          // 524288 B
  unsigned short* h0  = (unsigned short*)(ws + 1048576);         // 65,536,000 B
  unsigned short* h1  = (unsigned short*)(ws + 1048576 + 65536000ull);

  k_conv<<<500, 256, 0, stream>>>(x, conv_w, conv_b, y);
  k_cvtw1<<<1024, 256, 0, stream>>>(w_ih1, w1b);
  k_h0<<<32000, 256, 0, stream>>>(y, w_ih0, b_ih0, b_hh0, h0);
  k_gemm1<<<dim3(1000, 4), 256, 0, stream>>>(h0, w1b, b_ih1, b_hh1, h1);
  k_initout<<<500, 256, 0, stream>>>(fc_b, out);
  k_gemm2<<<dim3(4, 125), 512, 0, stream>>>(h1, fc_w, out);
}

// Round 4
// 402.994 us; speedup vs baseline: 1.3755x; 1.3755x over previous
//
#include <hip/hip_runtime.h>
#include <hip/hip_bf16.h>
#include <stdint.h>

#define B_   256
#define C_   10
#define S_   500
#define H_   256
#define OUT_ 500
#define M_   (B_ * S_)   // 128000 LSTM rows
#define FCK  (S_ * H_)   // 128000 fc inner dim

typedef __attribute__((ext_vector_type(8))) short s16x8;   // 8 bf16
typedef __attribute__((ext_vector_type(4))) float f32x4;

__device__ __forceinline__ unsigned short f2bf(float f) {
  union { float f; unsigned u; } v; v.f = f;
  unsigned r = v.u + 0x7fffu + ((v.u >> 16) & 1u);   // RNE
  return (unsigned short)(r >> 16);
}
__device__ __forceinline__ float sigf(float x) { return 1.0f / (1.0f + __expf(-x)); }
__device__ __forceinline__ float tanh_f(float x) { return 1.0f - 2.0f / (__expf(2.0f * x) + 1.0f); }

__device__ __forceinline__ void gload16(const void* g, void* l) {
  __builtin_amdgcn_global_load_lds((const __attribute__((address_space(1))) void*)g,
                                   (__attribute__((address_space(3))) void*)l, 16, 0, 0);
}

// ---- conv center tap + relu ----
__global__ void k_conv(const float* __restrict__ x, const float* __restrict__ cw,
                       const float* __restrict__ cb, float* __restrict__ y) {
  int n = blockIdx.x * 256 + threadIdx.x;            // 128000 exact
  int b = n / S_, s = n - b * S_;
  const float* xp = x + (size_t)b * C_ * S_ + s;
  float acc = cb[0];
#pragma unroll
  for (int c = 0; c < C_; ++c) acc += xp[c * S_] * cw[c * 5 + 2];
  y[n] = fmaxf(acc, 0.0f);
}

// ---- w_ih1 fp32 -> bf16 ----
__global__ void k_cvtw1(const float* __restrict__ w, unsigned short* __restrict__ wb) {
  int i = blockIdx.x * 256 + threadIdx.x;            // 262144 exact
  wb[i] = f2bf(w[i]);
}

// ---- LSTM0 (scalar input, zero state, f-gate dead): h0[n][k] bf16 ----
__global__ void k_h0(const float* __restrict__ y, const float* __restrict__ w0,
                     const float* __restrict__ bi0, const float* __restrict__ bh0,
                     unsigned short* __restrict__ h0) {
  int gid = blockIdx.x * 256 + threadIdx.x;          // 8,192,000 exact
  int n = gid >> 6, q = gid & 63;
  int k = q * 4;
  float yv = y[n];
  f32x4 wi = *(const f32x4*)&w0[k];
  f32x4 wg = *(const f32x4*)&w0[512 + k];
  f32x4 wo = *(const f32x4*)&w0[768 + k];
  f32x4 bii = *(const f32x4*)&bi0[k];
  f32x4 big = *(const f32x4*)&bi0[512 + k];
  f32x4 bio = *(const f32x4*)&bi0[768 + k];
  f32x4 bhi = *(const f32x4*)&bh0[k];
  f32x4 bhg = *(const f32x4*)&bh0[512 + k];
  f32x4 bho = *(const f32x4*)&bh0[768 + k];
  ushort4 o;
  unsigned short* op = (unsigned short*)&o;
#pragma unroll
  for (int j = 0; j < 4; ++j) {
    float gi = yv * wi[j] + bii[j] + bhi[j];
    float gg = yv * wg[j] + big[j] + bhg[j];
    float go = yv * wo[j] + bio[j] + bho[j];
    float c = sigf(gi) * tanh_f(gg);
    op[j] = f2bf(sigf(go) * tanh_f(c));
  }
  *(ushort4*)&h0[(size_t)n * 256 + k] = o;
}

// ---- GEMM1: gates = h0 @ Wb^T, fused act -> h1 TILED [k/64][256b][64] ----
// BM=128, 64 k-cols x 3 gates, BK=64, K=256; LDS staged, source-swizzled.
__global__ __launch_bounds__(256) void k_gemm1(
    const unsigned short* __restrict__ A,    // h0 [M][256] bf16
    const unsigned short* __restrict__ Wb,   // [1024][256] bf16
    const float* __restrict__ b1i, const float* __restrict__ b1h,
    unsigned short* __restrict__ h1t) {
  __shared__ __align__(16) unsigned short As[128 * 64];  // 16 KB
  __shared__ __align__(16) unsigned short Bs[192 * 64];  // 24 KB
  const int t = threadIdx.x, lane = t & 63, w = t >> 6;
  const int m0 = blockIdx.x * 128;
  const int kc0 = blockIdx.y * 64;
  f32x4 acc[2][3][4] = {};

  for (int kt = 0; kt < 4; ++kt) {
    // A: 1024 chunks (128 rows x 8); source col-chunk swizzled by row&7
#pragma unroll
    for (int it = 0; it < 4; ++it) {
      int q = it * 256 + t;
      int r = q >> 3, c = q & 7;
      gload16(A + (size_t)(m0 + r) * 256 + kt * 64 + ((c ^ (r & 7)) << 3),
              (void*)&As[q * 8]);
    }
    // B: 1536 chunks (192 rows x 8); gate g=r>>6 (i,g,o -> 0/512/768)
#pragma unroll
    for (int it = 0; it < 6; ++it) {
      int q = it * 256 + t;
      int r = q >> 3, c = q & 7;
      int g = r >> 6, kl = r & 63;
      int gbase = (g == 0) ? 0 : (g == 1 ? 512 : 768);
      gload16(Wb + (size_t)(gbase + kc0 + kl) * 256 + kt * 64 + ((c ^ (r & 7)) << 3),
              (void*)&Bs[q * 8]);
    }
    __syncthreads();
#pragma unroll
    for (int kk = 0; kk < 2; ++kk) {
      const int c0 = kk * 4 + (lane >> 4);
      const int ra0 = w * 32 + (lane & 15), ra1 = ra0 + 16;
      s16x8 a0 = *(const s16x8*)&As[ra0 * 64 + ((c0 ^ (ra0 & 7)) << 3)];
      s16x8 a1 = *(const s16x8*)&As[ra1 * 64 + ((c0 ^ (ra1 & 7)) << 3)];
#pragma unroll
      for (int g = 0; g < 3; ++g) {
#pragma unroll
        for (int n = 0; n < 4; ++n) {
          const int rb = g * 64 + n * 16 + (lane & 15);
          s16x8 b = *(const s16x8*)&Bs[rb * 64 + ((c0 ^ (rb & 7)) << 3)];
          acc[0][g][n] = __builtin_amdgcn_mfma_f32_16x16x32_bf16(a0, b, acc[0][g][n], 0, 0, 0);
          acc[1][g][n] = __builtin_amdgcn_mfma_f32_16x16x32_bf16(a1, b, acc[1][g][n], 0, 0, 0);
        }
      }
    }
    __syncthreads();
  }
  // epilogue: h = sig(go)*tanh(sig(gi)*tanh(gg)); write tiled:
  // kappa = s*256 + kglob; tile = s*4 + blockIdx.y; addr = tile*16384 + b*64 + (kglob&63)
#pragma unroll
  for (int n = 0; n < 4; ++n) {
    int kloc = n * 16 + (lane & 15);
    int kglob = kc0 + kloc;
    float bi = b1i[kglob] + b1h[kglob];
    float bg = b1i[512 + kglob] + b1h[512 + kglob];
    float bo = b1i[768 + kglob] + b1h[768 + kglob];
#pragma unroll
    for (int m = 0; m < 2; ++m) {
#pragma unroll
      for (int r = 0; r < 4; ++r) {
        int row = m0 + w * 32 + m * 16 + (lane >> 4) * 4 + r;
        int bb = row / 500, ss = row - bb * 500;
        float gi = acc[m][0][n][r] + bi;
        float gg = acc[m][1][n][r] + bg;
        float go = acc[m][2][n][r] + bo;
        float c = sigf(gi) * tanh_f(gg);
        h1t[(size_t)(ss * 4 + blockIdx.y) * 16384 + bb * 64 + (kloc)] =
            f2bf(sigf(go) * tanh_f(c));
      }
    }
  }
}

// ---- out init: out[b][o] = fc_b[o] ----
__global__ void k_initout(const float* __restrict__ fcb, float* __restrict__ out) {
  int i = blockIdx.x * 256 + threadIdx.x;            // 128000 exact
  out[i] = fcb[i % OUT_];
}

// ---- GEMM2: out += feat @ fc_w^T ; split-K + atomics ----
// BM=256, BN=64, Kchunk=1024, grid(8,125). A staged per-kt (single buf) from
// tiled h1t; W double-buffered; both source-swizzled; async 2-phase barriers.
__global__ __launch_bounds__(512, 2) void k_gemm2(
    const unsigned short* __restrict__ At,   // h1t tiled [2000][256][64] bf16
    const float* __restrict__ W,             // fc_w [500][128000] f32
    float* __restrict__ out) {
  __shared__ __align__(16) unsigned short As[256 * 64];  // 32 KB
  __shared__ __align__(16) float Ws[2][64 * 64];         // 2 x 16 KB
  const int t = threadIdx.x, lane = t & 63, w = t >> 6;
  const int n0 = blockIdx.x * 64;
  const int ky = blockIdx.y;
  const size_t kbase = (size_t)ky * 1024;
  f32x4 acc[2][4] = {};

  // W stage: 64 rows x 16 chunks = 1024; source col-chunk swizzled by row&15
#define STAGE_W(buf, kofs)                                                    \
  {                                                                           \
    _Pragma("unroll")                                                         \
    for (int it = 0; it < 2; ++it) {                                          \
      int q = it * 512 + t;                                                   \
      int r = q >> 4, c = q & 15;                                             \
      int nrow = n0 + r; if (nrow > 499) nrow = 499;                          \
      gload16(W + (size_t)nrow * FCK + (kofs) + ((c ^ (r & 15)) << 2),        \
              (void*)&Ws[buf][q * 4]);                                        \
    }                                                                         \
  }

  STAGE_W(0, kbase);               // W(kt=0); drains via first-iter vmcnt(2)

  int cur = 0;
  for (int kt = 0; kt < 16; ++kt) {
    // stage A tile (contiguous 32 KB): 2048 chunks, source-swizzled by row&7
#pragma unroll
    for (int it = 0; it < 4; ++it) {
      int q = it * 512 + t;
      int r = q >> 3, c = q & 7;
      gload16(At + (size_t)(ky * 16 + kt) * 16384 + r * 64 + ((c ^ (r & 7)) << 3),
              (void*)&As[q * 8]);
    }
    // stage next W tile
    int ktn = (kt < 15) ? (kt + 1) : 15;
    STAGE_W(cur ^ 1, kbase + (size_t)ktn * 64);
    // wait own A-loads (4) + prev W done; keep 2 newest (W-next) in flight
    asm volatile("s_waitcnt vmcnt(2)" ::: "memory");
    __builtin_amdgcn_s_barrier();
    __builtin_amdgcn_sched_barrier(0);
    // compute from As + Ws[cur]
#pragma unroll
    for (int kk = 0; kk < 2; ++kk) {
      s16x8 af[2];
#pragma unroll
      for (int m = 0; m < 2; ++m) {
        const int ra = w * 32 + m * 16 + (lane & 15);
        const int c0 = kk * 4 + (lane >> 4);
        af[m] = *(const s16x8*)&As[ra * 64 + ((c0 ^ (ra & 7)) << 3)];
      }
#pragma unroll
      for (int n = 0; n < 4; ++n) {
        const int br = n * 16 + (lane & 15);
        const int c0 = kk * 8 + (lane >> 4) * 2;
        const int cA = c0 ^ (br & 15), cB = (c0 + 1) ^ (br & 15);
        f32x4 w0 = *(const f32x4*)&Ws[cur][br * 64 + cA * 4];
        f32x4 w1 = *(const f32x4*)&Ws[cur][br * 64 + cB * 4];
        s16x8 b;
#pragma unroll
        for (int j = 0; j < 4; ++j) {
          b[j] = (short)f2bf(w0[j]);
          b[4 + j] = (short)f2bf(w1[j]);
        }
#pragma unroll
        for (int m = 0; m < 2; ++m)
          acc[m][n] = __builtin_amdgcn_mfma_f32_16x16x32_bf16(af[m], b, acc[m][n], 0, 0, 0);
      }
    }
    // all LDS reads done before As is restaged next iter; W-next stays in flight
    asm volatile("s_waitcnt lgkmcnt(0)" ::: "memory");
    __builtin_amdgcn_sched_barrier(0);
    __builtin_amdgcn_s_barrier();
    cur ^= 1;
  }

#pragma unroll
  for (int n = 0; n < 4; ++n) {
    int col = n0 + n * 16 + (lane & 15);
    if (col < OUT_) {
#pragma unroll
      for (int m = 0; m < 2; ++m) {
#pragma unroll
        for (int r = 0; r < 4; ++r) {
          int row = w * 32 + m * 16 + (lane >> 4) * 4 + r;
          atomicAdd(&out[(size_t)row * OUT_ + col], acc[m][n][r]);
        }
      }
    }
  }
#undef STAGE_W
}

extern "C" void kernel_launch(void* const* d_in, const int* in_sizes, int n_in,
                              void* d_out, int out_size, void* d_ws, size_t ws_size,
                              hipStream_t stream) {
  const float* x      = (const float*)d_in[0];
  const float* conv_w = (const float*)d_in[1];
  const float* conv_b = (const float*)d_in[2];
  const float* w_ih0  = (const float*)d_in[3];
  const float* b_ih0  = (const float*)d_in[4];
  const float* b_hh0  = (const float*)d_in[5];
  const float* w_ih1  = (const float*)d_in[6];
  const float* b_ih1  = (const float*)d_in[7];
  const float* b_hh1  = (const float*)d_in[8];
  const float* fc_w   = (const float*)d_in[9];
  const float* fc_b   = (const float*)d_in[10];
  float* out = (float*)d_out;

  char* ws = (char*)d_ws;
  float* y            = (float*)ws;                              // 512000 B
  unsigned short* w1b = (unsigned short*)(ws + 512000);          // 524288 B
  unsigned short* h0  = (unsigned short*)(ws + 1048576);         // 65,536,000 B
  unsigned short* h1t = (unsigned short*)(ws + 1048576 + 65536000ull);

  k_conv<<<500, 256, 0, stream>>>(x, conv_w, conv_b, y);
  k_cvtw1<<<1024, 256, 0, stream>>>(w_ih1, w1b);
  k_h0<<<32000, 256, 0, stream>>>(y, w_ih0, b_ih0, b_hh0, h0);
  k_gemm1<<<dim3(1000, 4), 256, 0, stream>>>(h0, w1b, b_ih1, b_hh1, h1t);
  k_initout<<<500, 256, 0, stream>>>(fc_b, out);
  k_gemm2<<<dim3(8, 125), 512, 0, stream>>>(h1t, fc_w, out);
}

// Round 5
// 374.215 us; speedup vs baseline: 1.4812x; 1.0769x over previous
//
#include <hip/hip_runtime.h>
#include <hip/hip_bf16.h>
#include <stdint.h>

#define B_   256
#define C_   10
#define S_   500
#define H_   256
#define OUT_ 500
#define M_   (B_ * S_)   // 128000 LSTM rows
#define FCK  (S_ * H_)   // 128000 fc inner dim

typedef __attribute__((ext_vector_type(8))) short s16x8;   // 8 bf16
typedef __attribute__((ext_vector_type(4))) float f32x4;

__device__ __forceinline__ unsigned short f2bf(float f) {
  union { float f; unsigned u; } v; v.f = f;
  unsigned r = v.u + 0x7fffu + ((v.u >> 16) & 1u);   // RNE
  return (unsigned short)(r >> 16);
}
__device__ __forceinline__ float sigf(float x) { return 1.0f / (1.0f + __expf(-x)); }
__device__ __forceinline__ float tanh_f(float x) { return 1.0f - 2.0f / (__expf(2.0f * x) + 1.0f); }

__device__ __forceinline__ void gload16(const void* g, void* l) {
  __builtin_amdgcn_global_load_lds((const __attribute__((address_space(1))) void*)g,
                                   (__attribute__((address_space(3))) void*)l, 16, 0, 0);
}

// pack 8 f32 -> 8 bf16 via v_cvt_pk_bf16_f32 (S0 in low 16 bits)
__device__ __forceinline__ s16x8 pack_bf16x8(f32x4 a, f32x4 b) {
  union { s16x8 v; unsigned u[4]; } r;
  asm("v_cvt_pk_bf16_f32 %0, %1, %2" : "=v"(r.u[0]) : "v"(a[0]), "v"(a[1]));
  asm("v_cvt_pk_bf16_f32 %0, %1, %2" : "=v"(r.u[1]) : "v"(a[2]), "v"(a[3]));
  asm("v_cvt_pk_bf16_f32 %0, %1, %2" : "=v"(r.u[2]) : "v"(b[0]), "v"(b[1]));
  asm("v_cvt_pk_bf16_f32 %0, %1, %2" : "=v"(r.u[3]) : "v"(b[2]), "v"(b[3]));
  return r.v;
}

// ---- conv center tap + relu ----
__global__ void k_conv(const float* __restrict__ x, const float* __restrict__ cw,
                       const float* __restrict__ cb, float* __restrict__ y) {
  int n = blockIdx.x * 256 + threadIdx.x;            // 128000 exact
  int b = n / S_, s = n - b * S_;
  const float* xp = x + (size_t)b * C_ * S_ + s;
  float acc = cb[0];
#pragma unroll
  for (int c = 0; c < C_; ++c) acc += xp[c * S_] * cw[c * 5 + 2];
  y[n] = fmaxf(acc, 0.0f);
}

// ---- w_ih1 fp32 -> bf16 ----
__global__ void k_cvtw1(const float* __restrict__ w, unsigned short* __restrict__ wb) {
  int i = blockIdx.x * 256 + threadIdx.x;            // 262144 exact
  wb[i] = f2bf(w[i]);
}

// ---- LSTM0 (scalar input, zero state, f-gate dead): h0[n][k] bf16 ----
__global__ void k_h0(const float* __restrict__ y, const float* __restrict__ w0,
                     const float* __restrict__ bi0, const float* __restrict__ bh0,
                     unsigned short* __restrict__ h0) {
  int gid = blockIdx.x * 256 + threadIdx.x;          // 8,192,000 exact
  int n = gid >> 6, q = gid & 63;
  int k = q * 4;
  float yv = y[n];
  f32x4 wi = *(const f32x4*)&w0[k];
  f32x4 wg = *(const f32x4*)&w0[512 + k];
  f32x4 wo = *(const f32x4*)&w0[768 + k];
  f32x4 bii = *(const f32x4*)&bi0[k];
  f32x4 big = *(const f32x4*)&bi0[512 + k];
  f32x4 bio = *(const f32x4*)&bi0[768 + k];
  f32x4 bhi = *(const f32x4*)&bh0[k];
  f32x4 bhg = *(const f32x4*)&bh0[512 + k];
  f32x4 bho = *(const f32x4*)&bh0[768 + k];
  ushort4 o;
  unsigned short* op = (unsigned short*)&o;
#pragma unroll
  for (int j = 0; j < 4; ++j) {
    float gi = yv * wi[j] + bii[j] + bhi[j];
    float gg = yv * wg[j] + big[j] + bhg[j];
    float go = yv * wo[j] + bio[j] + bho[j];
    float c = sigf(gi) * tanh_f(gg);
    op[j] = f2bf(sigf(go) * tanh_f(c));
  }
  *(ushort4*)&h0[(size_t)n * 256 + k] = o;
}

// ---- GEMM1: gates = h0 @ Wb^T, fused act -> h1 TILED [k/64][256b][64] ----
__global__ __launch_bounds__(256) void k_gemm1(
    const unsigned short* __restrict__ A,    // h0 [M][256] bf16
    const unsigned short* __restrict__ Wb,   // [1024][256] bf16
    const float* __restrict__ b1i, const float* __restrict__ b1h,
    unsigned short* __restrict__ h1t) {
  __shared__ __align__(16) unsigned short As[128 * 64];  // 16 KB
  __shared__ __align__(16) unsigned short Bs[192 * 64];  // 24 KB
  const int t = threadIdx.x, lane = t & 63, w = t >> 6;
  const int m0 = blockIdx.x * 128;
  const int kc0 = blockIdx.y * 64;
  f32x4 acc[2][3][4] = {};

  for (int kt = 0; kt < 4; ++kt) {
#pragma unroll
    for (int it = 0; it < 4; ++it) {
      int q = it * 256 + t;
      int r = q >> 3, c = q & 7;
      gload16(A + (size_t)(m0 + r) * 256 + kt * 64 + ((c ^ (r & 7)) << 3),
              (void*)&As[q * 8]);
    }
#pragma unroll
    for (int it = 0; it < 6; ++it) {
      int q = it * 256 + t;
      int r = q >> 3, c = q & 7;
      int g = r >> 6, kl = r & 63;
      int gbase = (g == 0) ? 0 : (g == 1 ? 512 : 768);
      gload16(Wb + (size_t)(gbase + kc0 + kl) * 256 + kt * 64 + ((c ^ (r & 7)) << 3),
              (void*)&Bs[q * 8]);
    }
    __syncthreads();
#pragma unroll
    for (int kk = 0; kk < 2; ++kk) {
      const int c0 = kk * 4 + (lane >> 4);
      const int ra0 = w * 32 + (lane & 15), ra1 = ra0 + 16;
      s16x8 a0 = *(const s16x8*)&As[ra0 * 64 + ((c0 ^ (ra0 & 7)) << 3)];
      s16x8 a1 = *(const s16x8*)&As[ra1 * 64 + ((c0 ^ (ra1 & 7)) << 3)];
#pragma unroll
      for (int g = 0; g < 3; ++g) {
#pragma unroll
        for (int n = 0; n < 4; ++n) {
          const int rb = g * 64 + n * 16 + (lane & 15);
          s16x8 b = *(const s16x8*)&Bs[rb * 64 + ((c0 ^ (rb & 7)) << 3)];
          acc[0][g][n] = __builtin_amdgcn_mfma_f32_16x16x32_bf16(a0, b, acc[0][g][n], 0, 0, 0);
          acc[1][g][n] = __builtin_amdgcn_mfma_f32_16x16x32_bf16(a1, b, acc[1][g][n], 0, 0, 0);
        }
      }
    }
    __syncthreads();
  }
#pragma unroll
  for (int n = 0; n < 4; ++n) {
    int kloc = n * 16 + (lane & 15);
    int kglob = kc0 + kloc;
    float bi = b1i[kglob] + b1h[kglob];
    float bg = b1i[512 + kglob] + b1h[512 + kglob];
    float bo = b1i[768 + kglob] + b1h[768 + kglob];
#pragma unroll
    for (int m = 0; m < 2; ++m) {
#pragma unroll
      for (int r = 0; r < 4; ++r) {
        int row = m0 + w * 32 + m * 16 + (lane >> 4) * 4 + r;
        int bb = row / 500, ss = row - bb * 500;
        float gi = acc[m][0][n][r] + bi;
        float gg = acc[m][1][n][r] + bg;
        float go = acc[m][2][n][r] + bo;
        float c = sigf(gi) * tanh_f(gg);
        h1t[(size_t)(ss * 4 + blockIdx.y) * 16384 + bb * 64 + kloc] =
            f2bf(sigf(go) * tanh_f(c));
      }
    }
  }
}

// ---- out init: out[b][o] = fc_b[o] ----
__global__ void k_initout(const float* __restrict__ fcb, float* __restrict__ out) {
  int i = blockIdx.x * 256 + threadIdx.x;            // 128000 exact
  out[i] = fcb[i % OUT_];
}

// ---- GEMM2: out += feat @ fc_w^T ; deep-pipelined split-K + atomics ----
// BM=256, BN=128, BK=32, Kchunk=1024; grid 500 linear (nx=4 x ky=125),
// chunked-XCD bijective remap. A 2-buf (2-ahead), W 3-buf (3-ahead),
// counted vmcnt(6) keeps the HBM stream continuous across barriers.
__global__ __launch_bounds__(512, 4) void k_gemm2(
    const unsigned short* __restrict__ At,   // h1t tiled [2000][256][64] bf16
    const float* __restrict__ W,             // fc_w [500][128000] f32
    float* __restrict__ out) {
  __shared__ __align__(16) unsigned short As[2][256 * 32];  // 2 x 16 KB
  __shared__ __align__(16) float Ws[3][128 * 32];           // 3 x 16 KB
  const int t = threadIdx.x, lane = t & 63, w = t >> 6;
  // bijective chunked XCD map for 500 blocks (q=62, r=4)
  const int orig = blockIdx.x;
  const int xcd = orig & 7, lin = orig >> 3;
  const int wgid = (xcd < 4 ? xcd * 63 : 252 + (xcd - 4) * 62) + lin;
  const int nx = wgid & 3, ky = wgid >> 2;
  const int n0 = nx * 128;
  const size_t kbase = (size_t)ky * 1024;
  f32x4 acc[2][8] = {};

  // A(kt): rows 0..255, feat cols [ky*1024+kt*32, +32). tile = ky*16+(kt>>1),
  // half = (kt&1)*32. 1024 chunks of 16B; source-swizzled by row&3.
#define STAGE_A(kt)                                                           \
  {                                                                           \
    const size_t tb = (size_t)(ky * 16 + ((kt) >> 1)) * 16384 + ((kt) & 1) * 32; \
    _Pragma("unroll")                                                         \
    for (int it = 0; it < 2; ++it) {                                          \
      int q = it * 512 + t;                                                   \
      int r = q >> 2, c = q & 3;                                              \
      gload16(At + tb + r * 64 + ((c ^ (r & 3)) << 3),                        \
              (void*)&As[(kt) & 1][q * 8]);                                   \
    }                                                                         \
  }
  // W(kt): 128 rows x 32 f32; 1024 chunks of 16B; source-swizzled by row&7.
#define STAGE_W(kt, buf)                                                      \
  {                                                                           \
    const size_t kofs = kbase + (size_t)(kt) * 32;                            \
    _Pragma("unroll")                                                         \
    for (int it = 0; it < 2; ++it) {                                          \
      int q = it * 512 + t;                                                   \
      int r = q >> 3, c = q & 7;                                              \
      int nrow = n0 + r; if (nrow > 499) nrow = 499;                          \
      gload16(W + (size_t)nrow * FCK + kofs + ((c ^ (r & 7)) << 2),           \
              (void*)&Ws[buf][q * 4]);                                        \
    }                                                                         \
  }

  // prologue: oldest-first = W0, A0, W1, A1, W2  (10 outstanding/thread)
  STAGE_W(0, 0);
  STAGE_A(0);
  STAGE_W(1, 1);
  STAGE_A(1);
  STAGE_W(2, 2);

  int wc = 0;  // W compute buf = kt % 3 (stage reuses same buf for kt+3)
  for (int kt = 0; kt < 32; ++kt) {
    if (kt <= 29)      asm volatile("s_waitcnt vmcnt(6)" ::: "memory");
    else if (kt == 30) asm volatile("s_waitcnt vmcnt(4)" ::: "memory");
    else               asm volatile("s_waitcnt vmcnt(0)" ::: "memory");
    __builtin_amdgcn_s_barrier();
    __builtin_amdgcn_sched_barrier(0);

    const unsigned short* a_ = As[kt & 1];
    const float* w_ = Ws[wc];
    s16x8 af[2];
#pragma unroll
    for (int m = 0; m < 2; ++m) {
      const int ra = w * 32 + m * 16 + (lane & 15);
      const int c0 = lane >> 4;
      af[m] = *(const s16x8*)&a_[ra * 32 + ((c0 ^ (ra & 3)) << 3)];
    }
#pragma unroll
    for (int n = 0; n < 8; ++n) {
      const int rb = n * 16 + (lane & 15);
      const int cb = (lane >> 4) * 2;
      const int cA = cb ^ (rb & 7), cB = (cb + 1) ^ (rb & 7);
      f32x4 w0 = *(const f32x4*)&w_[rb * 32 + cA * 4];
      f32x4 w1 = *(const f32x4*)&w_[rb * 32 + cB * 4];
      s16x8 b = pack_bf16x8(w0, w1);
      acc[0][n] = __builtin_amdgcn_mfma_f32_16x16x32_bf16(af[0], b, acc[0][n], 0, 0, 0);
      acc[1][n] = __builtin_amdgcn_mfma_f32_16x16x32_bf16(af[1], b, acc[1][n], 0, 0, 0);
    }
    asm volatile("s_waitcnt lgkmcnt(0)" ::: "memory");
    __builtin_amdgcn_sched_barrier(0);
    __builtin_amdgcn_s_barrier();
    if (kt <= 29) STAGE_A(kt + 2);          // -> As[kt&1] (just consumed)
    if (kt <= 28) STAGE_W(kt + 3, wc);      // -> Ws[wc]   (just consumed)
    wc = (wc == 2) ? 0 : wc + 1;
  }

#pragma unroll
  for (int n = 0; n < 8; ++n) {
    int col = n0 + n * 16 + (lane & 15);
    if (col < OUT_) {
#pragma unroll
      for (int m = 0; m < 2; ++m) {
#pragma unroll
        for (int r = 0; r < 4; ++r) {
          int row = w * 32 + m * 16 + (lane >> 4) * 4 + r;
          atomicAdd(&out[(size_t)row * OUT_ + col], acc[m][n][r]);
        }
      }
    }
  }
#undef STAGE_A
#undef STAGE_W
}

extern "C" void kernel_launch(void* const* d_in, const int* in_sizes, int n_in,
                              void* d_out, int out_size, void* d_ws, size_t ws_size,
                              hipStream_t stream) {
  const float* x      = (const float*)d_in[0];
  const float* conv_w = (const float*)d_in[1];
  const float* conv_b = (const float*)d_in[2];
  const float* w_ih0  = (const float*)d_in[3];
  const float* b_ih0  = (const float*)d_in[4];
  const float* b_hh0  = (const float*)d_in[5];
  const float* w_ih1  = (const float*)d_in[6];
  const float* b_ih1  = (const float*)d_in[7];
  const float* b_hh1  = (const float*)d_in[8];
  const float* fc_w   = (const float*)d_in[9];
  const float* fc_b   = (const float*)d_in[10];
  float* out = (float*)d_out;

  char* ws = (char*)d_ws;
  float* y            = (float*)ws;                              // 512000 B
  unsigned short* w1b = (unsigned short*)(ws + 512000);          // 524288 B
  unsigned short* h0  = (unsigned short*)(ws + 1048576);         // 65,536,000 B
  unsigned short* h1t = (unsigned short*)(ws + 1048576 + 65536000ull);

  k_conv<<<500, 256, 0, stream>>>(x, conv_w, conv_b, y);
  k_cvtw1<<<1024, 256, 0, stream>>>(w_ih1, w1b);
  k_h0<<<32000, 256, 0, stream>>>(y, w_ih0, b_ih0, b_hh0, h0);
  k_gemm1<<<dim3(1000, 4), 256, 0, stream>>>(h0, w1b, b_ih1, b_hh1, h1t);
  k_initout<<<500, 256, 0, stream>>>(fc_b, out);
  k_gemm2<<<500, 512, 0, stream>>>(h1t, fc_w, out);
}

// Round 6
// 366.568 us; speedup vs baseline: 1.5121x; 1.0209x over previous
//
#include <hip/hip_runtime.h>
#include <hip/hip_bf16.h>
#include <stdint.h>

#define B_   256
#define C_   10
#define S_   500
#define H_   256
#define OUT_ 500
#define M_   (B_ * S_)   // 128000 LSTM rows
#define FCK  (S_ * H_)   // 128000 fc inner dim

typedef __attribute__((ext_vector_type(8))) short s16x8;   // 8 bf16
typedef __attribute__((ext_vector_type(4))) float f32x4;

__device__ __forceinline__ unsigned short f2bf(float f) {
  union { float f; unsigned u; } v; v.f = f;
  unsigned r = v.u + 0x7fffu + ((v.u >> 16) & 1u);   // RNE
  return (unsigned short)(r >> 16);
}
__device__ __forceinline__ float sigf(float x) { return 1.0f / (1.0f + __expf(-x)); }
__device__ __forceinline__ float tanh_f(float x) { return 1.0f - 2.0f / (__expf(2.0f * x) + 1.0f); }

__device__ __forceinline__ void gload16(const void* g, void* l) {
  __builtin_amdgcn_global_load_lds((const __attribute__((address_space(1))) void*)g,
                                   (__attribute__((address_space(3))) void*)l, 16, 0, 0);
}

// pack 8 f32 -> 8 bf16 via v_cvt_pk_bf16_f32 (S0 in low 16 bits)
__device__ __forceinline__ s16x8 pack_bf16x8(f32x4 a, f32x4 b) {
  union { s16x8 v; unsigned u[4]; } r;
  asm("v_cvt_pk_bf16_f32 %0, %1, %2" : "=v"(r.u[0]) : "v"(a[0]), "v"(a[1]));
  asm("v_cvt_pk_bf16_f32 %0, %1, %2" : "=v"(r.u[1]) : "v"(a[2]), "v"(a[3]));
  asm("v_cvt_pk_bf16_f32 %0, %1, %2" : "=v"(r.u[2]) : "v"(b[0]), "v"(b[1]));
  asm("v_cvt_pk_bf16_f32 %0, %1, %2" : "=v"(r.u[3]) : "v"(b[2]), "v"(b[3]));
  return r.v;
}

// ---- conv center tap + relu ----
__global__ void k_conv(const float* __restrict__ x, const float* __restrict__ cw,
                       const float* __restrict__ cb, float* __restrict__ y) {
  int n = blockIdx.x * 256 + threadIdx.x;            // 128000 exact
  int b = n / S_, s = n - b * S_;
  const float* xp = x + (size_t)b * C_ * S_ + s;
  float acc = cb[0];
#pragma unroll
  for (int c = 0; c < C_; ++c) acc += xp[c * S_] * cw[c * 5 + 2];
  y[n] = fmaxf(acc, 0.0f);
}

// ---- w_ih1 fp32 -> bf16 ----
__global__ void k_cvtw1(const float* __restrict__ w, unsigned short* __restrict__ wb) {
  int i = blockIdx.x * 256 + threadIdx.x;            // 262144 exact
  wb[i] = f2bf(w[i]);
}

// ---- LSTM0 (scalar input, zero state, f-gate dead): h0[n][k] bf16 ----
__global__ void k_h0(const float* __restrict__ y, const float* __restrict__ w0,
                     const float* __restrict__ bi0, const float* __restrict__ bh0,
                     unsigned short* __restrict__ h0) {
  int gid = blockIdx.x * 256 + threadIdx.x;          // 8,192,000 exact
  int n = gid >> 6, q = gid & 63;
  int k = q * 4;
  float yv = y[n];
  f32x4 wi = *(const f32x4*)&w0[k];
  f32x4 wg = *(const f32x4*)&w0[512 + k];
  f32x4 wo = *(const f32x4*)&w0[768 + k];
  f32x4 bii = *(const f32x4*)&bi0[k];
  f32x4 big = *(const f32x4*)&bi0[512 + k];
  f32x4 bio = *(const f32x4*)&bi0[768 + k];
  f32x4 bhi = *(const f32x4*)&bh0[k];
  f32x4 bhg = *(const f32x4*)&bh0[512 + k];
  f32x4 bho = *(const f32x4*)&bh0[768 + k];
  ushort4 o;
  unsigned short* op = (unsigned short*)&o;
#pragma unroll
  for (int j = 0; j < 4; ++j) {
    float gi = yv * wi[j] + bii[j] + bhi[j];
    float gg = yv * wg[j] + big[j] + bhg[j];
    float go = yv * wo[j] + bio[j] + bho[j];
    float c = sigf(gi) * tanh_f(gg);
    op[j] = f2bf(sigf(go) * tanh_f(c));
  }
  *(ushort4*)&h0[(size_t)n * 256 + k] = o;
}

// ---- GEMM1: gates = h0 @ Wb^T, fused act -> h1 TILED [k/64][256b][64] ----
__global__ __launch_bounds__(256) void k_gemm1(
    const unsigned short* __restrict__ A,    // h0 [M][256] bf16
    const unsigned short* __restrict__ Wb,   // [1024][256] bf16
    const float* __restrict__ b1i, const float* __restrict__ b1h,
    unsigned short* __restrict__ h1t) {
  __shared__ __align__(16) unsigned short As[128 * 64];  // 16 KB
  __shared__ __align__(16) unsigned short Bs[192 * 64];  // 24 KB
  const int t = threadIdx.x, lane = t & 63, w = t >> 6;
  const int m0 = blockIdx.x * 128;
  const int kc0 = blockIdx.y * 64;
  f32x4 acc[2][3][4] = {};

  for (int kt = 0; kt < 4; ++kt) {
#pragma unroll
    for (int it = 0; it < 4; ++it) {
      int q = it * 256 + t;
      int r = q >> 3, c = q & 7;
      gload16(A + (size_t)(m0 + r) * 256 + kt * 64 + ((c ^ (r & 7)) << 3),
              (void*)&As[q * 8]);
    }
#pragma unroll
    for (int it = 0; it < 6; ++it) {
      int q = it * 256 + t;
      int r = q >> 3, c = q & 7;
      int g = r >> 6, kl = r & 63;
      int gbase = (g == 0) ? 0 : (g == 1 ? 512 : 768);
      gload16(Wb + (size_t)(gbase + kc0 + kl) * 256 + kt * 64 + ((c ^ (r & 7)) << 3),
              (void*)&Bs[q * 8]);
    }
    __syncthreads();
#pragma unroll
    for (int kk = 0; kk < 2; ++kk) {
      const int c0 = kk * 4 + (lane >> 4);
      const int ra0 = w * 32 + (lane & 15), ra1 = ra0 + 16;
      s16x8 a0 = *(const s16x8*)&As[ra0 * 64 + ((c0 ^ (ra0 & 7)) << 3)];
      s16x8 a1 = *(const s16x8*)&As[ra1 * 64 + ((c0 ^ (ra1 & 7)) << 3)];
#pragma unroll
      for (int g = 0; g < 3; ++g) {
#pragma unroll
        for (int n = 0; n < 4; ++n) {
          const int rb = g * 64 + n * 16 + (lane & 15);
          s16x8 b = *(const s16x8*)&Bs[rb * 64 + ((c0 ^ (rb & 7)) << 3)];
          acc[0][g][n] = __builtin_amdgcn_mfma_f32_16x16x32_bf16(a0, b, acc[0][g][n], 0, 0, 0);
          acc[1][g][n] = __builtin_amdgcn_mfma_f32_16x16x32_bf16(a1, b, acc[1][g][n], 0, 0, 0);
        }
      }
    }
    __syncthreads();
  }
#pragma unroll
  for (int n = 0; n < 4; ++n) {
    int kloc = n * 16 + (lane & 15);
    int kglob = kc0 + kloc;
    float bi = b1i[kglob] + b1h[kglob];
    float bg = b1i[512 + kglob] + b1h[512 + kglob];
    float bo = b1i[768 + kglob] + b1h[768 + kglob];
#pragma unroll
    for (int m = 0; m < 2; ++m) {
#pragma unroll
      for (int r = 0; r < 4; ++r) {
        int row = m0 + w * 32 + m * 16 + (lane >> 4) * 4 + r;
        int bb = row / 500, ss = row - bb * 500;
        float gi = acc[m][0][n][r] + bi;
        float gg = acc[m][1][n][r] + bg;
        float go = acc[m][2][n][r] + bo;
        float c = sigf(gi) * tanh_f(gg);
        h1t[(size_t)(ss * 4 + blockIdx.y) * 16384 + bb * 64 + kloc] =
            f2bf(sigf(go) * tanh_f(c));
      }
    }
  }
}

// ---- out init: out[b][o] = fc_b[o] ----
__global__ void k_initout(const float* __restrict__ fcb, float* __restrict__ out) {
  int i = blockIdx.x * 256 + threadIdx.x;            // 128000 exact
  out[i] = fcb[i % OUT_];
}

// ---- GEMM2 v3: W direct global->reg as B-fragment (no LDS for W); A in LDS ----
// grid 1000 = bx(8: N=64 strips) x ky(125: K=1024 chunks), 512 thr = 8 waves:
// mg=w>>2 (M-half 128 rows), nw=w&3 (16 N-rows). 16 iters of BK=64.
// A 2-buf gload_lds, 1 barrier/iter, static vmcnt(4) ledger (A=4 oldest, W=4 newer).
__global__ __launch_bounds__(512, 4) void k_gemm2(
    const unsigned short* __restrict__ At,   // h1t tiled [2000][256][64] bf16
    const float* __restrict__ W,             // fc_w [500][128000] f32
    float* __restrict__ out) {
  __shared__ __align__(16) unsigned short As[2][256 * 64];  // 2 x 32 KB
  const int t = threadIdx.x, lane = t & 63, w = t >> 6;
  const int mg = w >> 2, nw = w & 3;
  // XCD-chunked bijective map (1000 % 8 == 0)
  const int orig = blockIdx.x;
  const int wgid = (orig & 7) * 125 + (orig >> 3);
  const int bx = wgid & 7, ky = wgid >> 3;
  const int n0 = bx * 64;
  const int wrow = n0 + nw * 16 + (lane & 15);
  const int wr = wrow > 499 ? 499 : wrow;
  const float* wp = W + (size_t)wr * FCK + (size_t)ky * 1024 + ((lane >> 4) * 8);

  // A(kt) tile = h1t block (ky*16+kt): 256 rows x 64 bf16 = 2048 16B-chunks.
#define STAGE_A2(kt, buf)                                                     \
  {                                                                           \
    const unsigned short* src = At + (size_t)(ky * 16 + (kt)) * 16384;        \
    _Pragma("unroll")                                                         \
    for (int it = 0; it < 4; ++it) {                                          \
      int q = it * 512 + t;                                                   \
      int r = q >> 3, c = q & 7;                                              \
      gload16(src + r * 64 + ((c ^ (r & 7)) << 3), (void*)&As[buf][q * 8]);   \
    }                                                                         \
  }

  f32x4 acc[8] = {};
  f32x4 wreg[2][4];   // [kt&1][kk*2+half] — all indices static (full unroll)

  STAGE_A2(0, 0);
#pragma unroll
  for (int j = 0; j < 4; ++j)
    wreg[0][j] = *(const f32x4*)(wp + (j >> 1) * 32 + (j & 1) * 4);

#pragma unroll
  for (int kt = 0; kt < 16; ++kt) {
    __builtin_amdgcn_sched_barrier(0);
    asm volatile("s_waitcnt vmcnt(4)" ::: "memory");  // A(kt) done; W(kt) stays
    __builtin_amdgcn_s_barrier();
    __builtin_amdgcn_sched_barrier(0);
    if (kt < 15) STAGE_A2(kt + 1, (kt + 1) & 1);      // lands during compute
    // first use of wreg[kt&1] -> compiler inserts its own counted wait
    s16x8 b0 = pack_bf16x8(wreg[kt & 1][0], wreg[kt & 1][1]);
    s16x8 b1 = pack_bf16x8(wreg[kt & 1][2], wreg[kt & 1][3]);
    if (kt < 15) {
#pragma unroll
      for (int j = 0; j < 4; ++j)
        wreg[(kt + 1) & 1][j] =
            *(const f32x4*)(wp + (kt + 1) * 64 + (j >> 1) * 32 + (j & 1) * 4);
    }
#pragma unroll
    for (int m = 0; m < 8; ++m) {
      const int ra = mg * 128 + m * 16 + (lane & 15);
      const int c0 = (lane >> 4);
      s16x8 a0 = *(const s16x8*)&As[kt & 1][ra * 64 + ((c0 ^ (ra & 7)) << 3)];
      acc[m] = __builtin_amdgcn_mfma_f32_16x16x32_bf16(a0, b0, acc[m], 0, 0, 0);
    }
#pragma unroll
    for (int m = 0; m < 8; ++m) {
      const int ra = mg * 128 + m * 16 + (lane & 15);
      const int c1 = 4 + (lane >> 4);
      s16x8 a1 = *(const s16x8*)&As[kt & 1][ra * 64 + ((c1 ^ (ra & 7)) << 3)];
      acc[m] = __builtin_amdgcn_mfma_f32_16x16x32_bf16(a1, b1, acc[m], 0, 0, 0);
    }
  }

  const int col = n0 + nw * 16 + (lane & 15);
  if (col < OUT_) {
#pragma unroll
    for (int m = 0; m < 8; ++m) {
#pragma unroll
      for (int r = 0; r < 4; ++r) {
        int row = mg * 128 + m * 16 + (lane >> 4) * 4 + r;
        atomicAdd(&out[(size_t)row * OUT_ + col], acc[m][r]);
      }
    }
  }
#undef STAGE_A2
}

extern "C" void kernel_launch(void* const* d_in, const int* in_sizes, int n_in,
                              void* d_out, int out_size, void* d_ws, size_t ws_size,
                              hipStream_t stream) {
  const float* x      = (const float*)d_in[0];
  const float* conv_w = (const float*)d_in[1];
  const float* conv_b = (const float*)d_in[2];
  const float* w_ih0  = (const float*)d_in[3];
  const float* b_ih0  = (const float*)d_in[4];
  const float* b_hh0  = (const float*)d_in[5];
  const float* w_ih1  = (const float*)d_in[6];
  const float* b_ih1  = (const float*)d_in[7];
  const float* b_hh1  = (const float*)d_in[8];
  const float* fc_w   = (const float*)d_in[9];
  const float* fc_b   = (const float*)d_in[10];
  float* out = (float*)d_out;

  char* ws = (char*)d_ws;
  float* y            = (float*)ws;                              // 512000 B
  unsigned short* w1b = (unsigned short*)(ws + 512000);          // 524288 B
  unsigned short* h0  = (unsigned short*)(ws + 1048576);         // 65,536,000 B
  unsigned short* h1t = (unsigned short*)(ws + 1048576 + 65536000ull);

  k_conv<<<500, 256, 0, stream>>>(x, conv_w, conv_b, y);
  k_cvtw1<<<1024, 256, 0, stream>>>(w_ih1, w1b);
  k_h0<<<32000, 256, 0, stream>>>(y, w_ih0, b_ih0, b_hh0, h0);
  k_gemm1<<<dim3(1000, 4), 256, 0, stream>>>(h0, w1b, b_ih1, b_hh1, h1t);
  k_initout<<<500, 256, 0, stream>>>(fc_b, out);
  k_gemm2<<<1000, 512, 0, stream>>>(h1t, fc_w, out);
}

// Round 7
// 323.214 us; speedup vs baseline: 1.7150x; 1.1341x over previous
//
#include <hip/hip_runtime.h>
#include <hip/hip_bf16.h>
#include <stdint.h>

#define B_   256
#define C_   10
#define S_   500
#define H_   256
#define OUT_ 500
#define M_   (B_ * S_)   // 128000 LSTM rows
#define FCK  (S_ * H_)   // 128000 fc inner dim

typedef __attribute__((ext_vector_type(8))) short s16x8;   // 8 bf16
typedef __attribute__((ext_vector_type(4))) float f32x4;

__device__ __forceinline__ unsigned short f2bf(float f) {
  union { float f; unsigned u; } v; v.f = f;
  unsigned r = v.u + 0x7fffu + ((v.u >> 16) & 1u);   // RNE
  return (unsigned short)(r >> 16);
}
__device__ __forceinline__ float sigf(float x) { return 1.0f / (1.0f + __expf(-x)); }
__device__ __forceinline__ float tanh_f(float x) { return 1.0f - 2.0f / (__expf(2.0f * x) + 1.0f); }

__device__ __forceinline__ void gload16(const void* g, void* l) {
  __builtin_amdgcn_global_load_lds((const __attribute__((address_space(1))) void*)g,
                                   (__attribute__((address_space(3))) void*)l, 16, 0, 0);
}

// pack 8 f32 -> 8 bf16 via v_cvt_pk_bf16_f32 (S0 in low 16 bits)
__device__ __forceinline__ s16x8 pack_bf16x8(f32x4 a, f32x4 b) {
  union { s16x8 v; unsigned u[4]; } r;
  asm("v_cvt_pk_bf16_f32 %0, %1, %2" : "=v"(r.u[0]) : "v"(a[0]), "v"(a[1]));
  asm("v_cvt_pk_bf16_f32 %0, %1, %2" : "=v"(r.u[1]) : "v"(a[2]), "v"(a[3]));
  asm("v_cvt_pk_bf16_f32 %0, %1, %2" : "=v"(r.u[2]) : "v"(b[0]), "v"(b[1]));
  asm("v_cvt_pk_bf16_f32 %0, %1, %2" : "=v"(r.u[3]) : "v"(b[2]), "v"(b[3]));
  return r.v;
}

// ---- conv center tap + relu ----
__global__ void k_conv(const float* __restrict__ x, const float* __restrict__ cw,
                       const float* __restrict__ cb, float* __restrict__ y) {
  int n = blockIdx.x * 256 + threadIdx.x;            // 128000 exact
  int b = n / S_, s = n - b * S_;
  const float* xp = x + (size_t)b * C_ * S_ + s;
  float acc = cb[0];
#pragma unroll
  for (int c = 0; c < C_; ++c) acc += xp[c * S_] * cw[c * 5 + 2];
  y[n] = fmaxf(acc, 0.0f);
}

// ---- w_ih1 fp32 -> bf16 ----
__global__ void k_cvtw1(const float* __restrict__ w, unsigned short* __restrict__ wb) {
  int i = blockIdx.x * 256 + threadIdx.x;            // 262144 exact
  wb[i] = f2bf(w[i]);
}

// ---- LSTM0 (scalar input, zero state, f-gate dead): h0[n][k] bf16 ----
__global__ void k_h0(const float* __restrict__ y, const float* __restrict__ w0,
                     const float* __restrict__ bi0, const float* __restrict__ bh0,
                     unsigned short* __restrict__ h0) {
  int gid = blockIdx.x * 256 + threadIdx.x;          // 8,192,000 exact
  int n = gid >> 6, q = gid & 63;
  int k = q * 4;
  float yv = y[n];
  f32x4 wi = *(const f32x4*)&w0[k];
  f32x4 wg = *(const f32x4*)&w0[512 + k];
  f32x4 wo = *(const f32x4*)&w0[768 + k];
  f32x4 bii = *(const f32x4*)&bi0[k];
  f32x4 big = *(const f32x4*)&bi0[512 + k];
  f32x4 bio = *(const f32x4*)&bi0[768 + k];
  f32x4 bhi = *(const f32x4*)&bh0[k];
  f32x4 bhg = *(const f32x4*)&bh0[512 + k];
  f32x4 bho = *(const f32x4*)&bh0[768 + k];
  ushort4 o;
  unsigned short* op = (unsigned short*)&o;
#pragma unroll
  for (int j = 0; j < 4; ++j) {
    float gi = yv * wi[j] + bii[j] + bhi[j];
    float gg = yv * wg[j] + big[j] + bhg[j];
    float go = yv * wo[j] + bio[j] + bho[j];
    float c = sigf(gi) * tanh_f(gg);
    op[j] = f2bf(sigf(go) * tanh_f(c));
  }
  *(ushort4*)&h0[(size_t)n * 256 + k] = o;
}

// ---- GEMM1: gates = h0 @ Wb^T, fused act -> h1 TILED [k/64][256b][64] ----
__global__ __launch_bounds__(256) void k_gemm1(
    const unsigned short* __restrict__ A,    // h0 [M][256] bf16
    const unsigned short* __restrict__ Wb,   // [1024][256] bf16
    const float* __restrict__ b1i, const float* __restrict__ b1h,
    unsigned short* __restrict__ h1t) {
  __shared__ __align__(16) unsigned short As[128 * 64];  // 16 KB
  __shared__ __align__(16) unsigned short Bs[192 * 64];  // 24 KB
  const int t = threadIdx.x, lane = t & 63, w = t >> 6;
  const int m0 = blockIdx.x * 128;
  const int kc0 = blockIdx.y * 64;
  f32x4 acc[2][3][4] = {};

  for (int kt = 0; kt < 4; ++kt) {
#pragma unroll
    for (int it = 0; it < 4; ++it) {
      int q = it * 256 + t;
      int r = q >> 3, c = q & 7;
      gload16(A + (size_t)(m0 + r) * 256 + kt * 64 + ((c ^ (r & 7)) << 3),
              (void*)&As[q * 8]);
    }
#pragma unroll
    for (int it = 0; it < 6; ++it) {
      int q = it * 256 + t;
      int r = q >> 3, c = q & 7;
      int g = r >> 6, kl = r & 63;
      int gbase = (g == 0) ? 0 : (g == 1 ? 512 : 768);
      gload16(Wb + (size_t)(gbase + kc0 + kl) * 256 + kt * 64 + ((c ^ (r & 7)) << 3),
              (void*)&Bs[q * 8]);
    }
    __syncthreads();
#pragma unroll
    for (int kk = 0; kk < 2; ++kk) {
      const int c0 = kk * 4 + (lane >> 4);
      const int ra0 = w * 32 + (lane & 15), ra1 = ra0 + 16;
      s16x8 a0 = *(const s16x8*)&As[ra0 * 64 + ((c0 ^ (ra0 & 7)) << 3)];
      s16x8 a1 = *(const s16x8*)&As[ra1 * 64 + ((c0 ^ (ra1 & 7)) << 3)];
#pragma unroll
      for (int g = 0; g < 3; ++g) {
#pragma unroll
        for (int n = 0; n < 4; ++n) {
          const int rb = g * 64 + n * 16 + (lane & 15);
          s16x8 b = *(const s16x8*)&Bs[rb * 64 + ((c0 ^ (rb & 7)) << 3)];
          acc[0][g][n] = __builtin_amdgcn_mfma_f32_16x16x32_bf16(a0, b, acc[0][g][n], 0, 0, 0);
          acc[1][g][n] = __builtin_amdgcn_mfma_f32_16x16x32_bf16(a1, b, acc[1][g][n], 0, 0, 0);
        }
      }
    }
    __syncthreads();
  }
#pragma unroll
  for (int n = 0; n < 4; ++n) {
    int kloc = n * 16 + (lane & 15);
    int kglob = kc0 + kloc;
    float bi = b1i[kglob] + b1h[kglob];
    float bg = b1i[512 + kglob] + b1h[512 + kglob];
    float bo = b1i[768 + kglob] + b1h[768 + kglob];
#pragma unroll
    for (int m = 0; m < 2; ++m) {
#pragma unroll
      for (int r = 0; r < 4; ++r) {
        int row = m0 + w * 32 + m * 16 + (lane >> 4) * 4 + r;
        int bb = row / 500, ss = row - bb * 500;
        float gi = acc[m][0][n][r] + bi;
        float gg = acc[m][1][n][r] + bg;
        float go = acc[m][2][n][r] + bo;
        float c = sigf(gi) * tanh_f(gg);
        h1t[(size_t)(ss * 4 + blockIdx.y) * 16384 + bb * 64 + kloc] =
            f2bf(sigf(go) * tanh_f(c));
      }
    }
  }
}

// ---- GEMM2: W direct global->reg as B-fragment; A in LDS; NO atomics ----
// grid 1000 = bx(8: N=64 strips) x ky(125: K=1024 chunks); writes f32
// partials part[ky][256][500] (streaming stores, zero contention).
__global__ __launch_bounds__(512, 4) void k_gemm2(
    const unsigned short* __restrict__ At,   // h1t tiled [2000][256][64] bf16
    const float* __restrict__ W,             // fc_w [500][128000] f32
    float* __restrict__ part) {              // [125][256][500] f32
  __shared__ __align__(16) unsigned short As[2][256 * 64];  // 2 x 32 KB
  const int t = threadIdx.x, lane = t & 63, w = t >> 6;
  const int mg = w >> 2, nw = w & 3;
  // XCD-chunked bijective map (1000 % 8 == 0)
  const int orig = blockIdx.x;
  const int wgid = (orig & 7) * 125 + (orig >> 3);
  const int bx = wgid & 7, ky = wgid >> 3;
  const int n0 = bx * 64;
  const int wrow = n0 + nw * 16 + (lane & 15);
  const int wr = wrow > 499 ? 499 : wrow;
  const float* wp = W + (size_t)wr * FCK + (size_t)ky * 1024 + ((lane >> 4) * 8);

#define STAGE_A2(kt, buf)                                                     \
  {                                                                           \
    const unsigned short* src = At + (size_t)(ky * 16 + (kt)) * 16384;        \
    _Pragma("unroll")                                                         \
    for (int it = 0; it < 4; ++it) {                                          \
      int q = it * 512 + t;                                                   \
      int r = q >> 3, c = q & 7;                                              \
      gload16(src + r * 64 + ((c ^ (r & 7)) << 3), (void*)&As[buf][q * 8]);   \
    }                                                                         \
  }

  f32x4 acc[8] = {};
  f32x4 wreg[2][4];   // [kt&1][j] — all indices static (full unroll)

  STAGE_A2(0, 0);
#pragma unroll
  for (int j = 0; j < 4; ++j)
    wreg[0][j] = *(const f32x4*)(wp + (j >> 1) * 32 + (j & 1) * 4);

#pragma unroll
  for (int kt = 0; kt < 16; ++kt) {
    __builtin_amdgcn_sched_barrier(0);
    asm volatile("s_waitcnt vmcnt(4)" ::: "memory");  // A(kt) done; W(kt) stays
    __builtin_amdgcn_s_barrier();
    __builtin_amdgcn_sched_barrier(0);
    if (kt < 15) STAGE_A2(kt + 1, (kt + 1) & 1);      // lands during compute
    s16x8 b0 = pack_bf16x8(wreg[kt & 1][0], wreg[kt & 1][1]);
    s16x8 b1 = pack_bf16x8(wreg[kt & 1][2], wreg[kt & 1][3]);
    if (kt < 15) {
#pragma unroll
      for (int j = 0; j < 4; ++j)
        wreg[(kt + 1) & 1][j] =
            *(const f32x4*)(wp + (kt + 1) * 64 + (j >> 1) * 32 + (j & 1) * 4);
    }
#pragma unroll
    for (int m = 0; m < 8; ++m) {
      const int ra = mg * 128 + m * 16 + (lane & 15);
      const int c0 = (lane >> 4);
      s16x8 a0 = *(const s16x8*)&As[kt & 1][ra * 64 + ((c0 ^ (ra & 7)) << 3)];
      acc[m] = __builtin_amdgcn_mfma_f32_16x16x32_bf16(a0, b0, acc[m], 0, 0, 0);
    }
#pragma unroll
    for (int m = 0; m < 8; ++m) {
      const int ra = mg * 128 + m * 16 + (lane & 15);
      const int c1 = 4 + (lane >> 4);
      s16x8 a1 = *(const s16x8*)&As[kt & 1][ra * 64 + ((c1 ^ (ra & 7)) << 3)];
      acc[m] = __builtin_amdgcn_mfma_f32_16x16x32_bf16(a1, b1, acc[m], 0, 0, 0);
    }
  }

  const int col = n0 + nw * 16 + (lane & 15);
  if (col < OUT_) {
    float* pp = part + (size_t)ky * (256 * OUT_);
#pragma unroll
    for (int m = 0; m < 8; ++m) {
#pragma unroll
      for (int r = 0; r < 4; ++r) {
        int row = mg * 128 + m * 16 + (lane >> 4) * 4 + r;
        pp[row * OUT_ + col] = acc[m][r];
      }
    }
  }
#undef STAGE_A2
}

// ---- reduce: out[i] = fc_b[i%500] + sum_ky part[ky][i] ----
__global__ void k_reduce(const float* __restrict__ part,
                         const float* __restrict__ fcb,
                         float* __restrict__ out) {
  int i = blockIdx.x * 256 + threadIdx.x;            // 128000 exact
  int col = i % OUT_;
  float s = fcb[col];
  const float* p = part + i;
#pragma unroll 5
  for (int ky = 0; ky < 125; ++ky) s += p[(size_t)ky * (256 * OUT_)];
  out[i] = s;
}

extern "C" void kernel_launch(void* const* d_in, const int* in_sizes, int n_in,
                              void* d_out, int out_size, void* d_ws, size_t ws_size,
                              hipStream_t stream) {
  const float* x      = (const float*)d_in[0];
  const float* conv_w = (const float*)d_in[1];
  const float* conv_b = (const float*)d_in[2];
  const float* w_ih0  = (const float*)d_in[3];
  const float* b_ih0  = (const float*)d_in[4];
  const float* b_hh0  = (const float*)d_in[5];
  const float* w_ih1  = (const float*)d_in[6];
  const float* b_ih1  = (const float*)d_in[7];
  const float* b_hh1  = (const float*)d_in[8];
  const float* fc_w   = (const float*)d_in[9];
  const float* fc_b   = (const float*)d_in[10];
  float* out = (float*)d_out;

  char* ws = (char*)d_ws;
  float* y            = (float*)ws;                              // 512000 B
  unsigned short* w1b = (unsigned short*)(ws + 512000);          // 524288 B
  unsigned short* h0  = (unsigned short*)(ws + 1048576);         // 65,536,000 B
  unsigned short* h1t = (unsigned short*)(ws + 1048576 + 65536000ull);
  // partials reuse h0's region (h0 is dead after k_gemm1): 64,000,000 B
  float* part         = (float*)(ws + 1048576);

  k_conv<<<500, 256, 0, stream>>>(x, conv_w, conv_b, y);
  k_cvtw1<<<1024, 256, 0, stream>>>(w_ih1, w1b);
  k_h0<<<32000, 256, 0, stream>>>(y, w_ih0, b_ih0, b_hh0, h0);
  k_gemm1<<<dim3(1000, 4), 256, 0, stream>>>(h0, w1b, b_ih1, b_hh1, h1t);
  k_gemm2<<<1000, 512, 0, stream>>>(h1t, fc_w, part);
  k_reduce<<<500, 256, 0, stream>>>(part, fc_b, out);
}